// Round 6
// baseline (299.287 us; speedup 1.0000x reference)
//
#include <hip/hip_runtime.h>

// Problem constants
constexpr int B    = 32;
constexpr int CIN  = 64;
constexpr int COUT = 128;
constexpr int T    = 300;
constexpr int V    = 25;
constexpr int TV   = T * V;            // 7500
constexpr long long NPC   = (long long)B * TV;          // 240000 per channel
constexpr long long TOTAL = (long long)B * COUT * TV;   // 30,720,000

typedef short          bf16x8 __attribute__((ext_vector_type(8)));
typedef float          f32x4  __attribute__((ext_vector_type(4)));
typedef unsigned short us8    __attribute__((ext_vector_type(8)));
typedef unsigned short us4    __attribute__((ext_vector_type(4)));

static __device__ __forceinline__ unsigned short f2bf(float f) {
  union { float f; unsigned u; } x; x.f = f;
  unsigned r = x.u + 0x7FFFu + ((x.u >> 16) & 1u);   // RNE
  return (unsigned short)(r >> 16);
}
static __device__ __forceinline__ float bf2f(unsigned short u) {
  union { unsigned u; float f; } x; x.u = ((unsigned)u) << 16;
  return x.f;
}

// swizzled offsets (in shorts). XOR at 16B-slot granularity.
static __device__ __forceinline__ int xoff(int pos, int c) {      // [pos][c<64]
  return pos * 64 + ((((c >> 3)) ^ (pos & 7)) << 3) + (c & 7);
}
static __device__ __forceinline__ int soff(int c, int pw) {       // [c][pw<128]
  return c * 128 + ((((pw >> 3)) ^ (c & 7)) << 3) + (pw & 7);
}

// ---------------------------------------------------------------------------
// kWT: temporal weights -> bf16, wb2[k][cblk=c>>3][o][e=c&7]
// ---------------------------------------------------------------------------
__global__ __launch_bounds__(256) void kWT(const float* __restrict__ w_t,
                                           unsigned short* __restrict__ wb2) {
  int i = blockIdx.x * 256 + threadIdx.x;
  if (i >= COUT * 9 * COUT) return;
  int c = i & 127, ok = i >> 7;
  int k = ok % 9, o = ok / 9;
  int idx = ((k * 16 + (c >> 3)) * 128 + o) * 8 + (c & 7);
  wb2[idx] = f2bf(w_t[(o * COUT + c) * 9 + k]);
}

// ---------------------------------------------------------------------------
// kW2: stacked 1x1 weights -> bf16, wrs2[cblk][row][e]; rows 0-127 w_r, 128-255 w_sp
// ---------------------------------------------------------------------------
__global__ __launch_bounds__(256) void kW2(const float* __restrict__ w_r,
                                           const float* __restrict__ w_sp,
                                           unsigned short* __restrict__ wrs2) {
  int i = blockIdx.x * 256 + threadIdx.x;
  if (i >= 256 * CIN) return;
  int c = i & 63, row = i >> 6;
  float v = (row < COUT) ? w_r[row * CIN + c] : w_sp[(row - COUT) * CIN + c];
  wrs2[((c >> 3) * 256 + row) * 8 + (c & 7)] = f2bf(v);
}

// ---------------------------------------------------------------------------
// kWB: block-diagonal graph matrix, bdt[pv][pw] (112x128 bf16)
// ---------------------------------------------------------------------------
__global__ __launch_bounds__(256) void kWB(const float* __restrict__ A_hat,
                                           unsigned short* __restrict__ bdt) {
  int i = blockIdx.x * 256 + threadIdx.x;
  if (i >= 112 * 128) return;
  int pv = i >> 7, pw = i & 127;
  float v = 0.f;
  if (pv < 100 && pw < 100 && (pv / 25) == (pw / 25))
    v = A_hat[(pv % 25) * 25 + (pw % 25)];
  bdt[i] = f2bf(v);
}

// ---------------------------------------------------------------------------
// kA4: all-MFMA spatial front-end + fused BN-stats partials.
// grid (75, 32), 4 waves. Outputs resb bf16 [b][c][pos], h bf16 [b][pos][c],
// part_rs[bid][wave][64] float2 (sum, sumsq) per channel row.
// ---------------------------------------------------------------------------
__global__ __launch_bounds__(256, 2) void kA4(
    const float* __restrict__ x, const unsigned short* __restrict__ bdt,
    const unsigned short* __restrict__ wrs2,
    unsigned short* __restrict__ resb, unsigned short* __restrict__ h,
    float2* __restrict__ part_rs)
{
  __shared__ unsigned short xs[64 * 128];    // 16 KB  [c][pw]  swizzled
  __shared__ unsigned short xsp[112 * 64];   // 14 KB  [pos][c] swizzled
  __shared__ unsigned short axsp[112 * 64];  // 14 KB  [pv][c]  swizzled

  const int tid  = threadIdx.x;
  const int lane = tid & 63;
  const int wave = tid >> 6;
  const int b    = blockIdx.y;
  const int p0   = blockIdx.x * 100;
  const int grp  = lane >> 4;
  const int l15  = lane & 15;

  for (int u = tid; u < 16 * 128; u += 256) {
    int pos = u & 127, c4 = u >> 7;
    int c0 = c4 * 4;
    float v0 = 0.f, v1 = 0.f, v2 = 0.f, v3 = 0.f;
    if (pos < 100) {
      const float* xp = &x[(b * CIN + c0) * TV + p0 + pos];
      v0 = xp[0]; v1 = xp[TV]; v2 = xp[2 * TV]; v3 = xp[3 * TV];
    }
    unsigned short b0 = f2bf(v0), b1 = f2bf(v1), b2 = f2bf(v2), b3 = f2bf(v3);
    xs[soff(c0,     pos)] = b0;
    xs[soff(c0 + 1, pos)] = b1;
    xs[soff(c0 + 2, pos)] = b2;
    xs[soff(c0 + 3, pos)] = b3;
    if (pos < 112) {
      us4 pk = {b0, b1, b2, b3};
      *(us4*)&xsp[xoff(pos, c0)] = pk;
    }
  }
  __syncthreads();

  // mix GEMM (sparse block-diagonal k-steps, table VERIFIED round 5)
  bf16x8 xf[4];
#pragma unroll
  for (int ks = 0; ks < 4; ++ks)
    xf[ks] = *(const bf16x8*)&xs[soff(wave * 16 + l15, ks * 32 + grp * 8)];

  {
    f32x4 macc[7];
#pragma unroll
    for (int ni = 0; ni < 7; ++ni) macc[ni] = (f32x4)0.f;
    const int kst[7] = {0, 0, 0, 0, 1, 2, 2};
    const int kcn[7] = {1, 2, 2, 3, 3, 2, 2};
#pragma unroll
    for (int ni = 0; ni < 7; ++ni) {
      for (int kk = 0; kk < kcn[ni]; ++kk) {
        int ks = kst[ni] + kk;
        bf16x8 gf = *(const bf16x8*)&bdt[(ni * 16 + l15) * 128 + ks * 32 + grp * 8];
        macc[ni] = __builtin_amdgcn_mfma_f32_16x16x32_bf16(xf[ks], gf, macc[ni], 0, 0, 0);
      }
    }
#pragma unroll
    for (int ni = 0; ni < 7; ++ni) {
#pragma unroll
      for (int r = 0; r < 4; ++r)
        axsp[xoff(ni * 16 + l15, wave * 16 + grp * 4 + r)] = f2bf(macc[ni][r]);
    }
  }
  __syncthreads();

  // channel GEMMs
  const unsigned short* bsrc = (wave < 2) ? xsp : axsp;
  f32x4 acc[4][7];
#pragma unroll
  for (int m = 0; m < 4; ++m)
#pragma unroll
    for (int n = 0; n < 7; ++n) acc[m][n] = (f32x4)0.f;

#pragma unroll
  for (int ks = 0; ks < 2; ++ks) {
    bf16x8 af[4], bfr[7];
#pragma unroll
    for (int mi = 0; mi < 4; ++mi) {
      int row = wave * 64 + mi * 16 + l15;
      af[mi] = *(const bf16x8*)&wrs2[((ks * 4 + grp) * 256 + row) * 8];
    }
#pragma unroll
    for (int ni = 0; ni < 7; ++ni)
      bfr[ni] = *(const bf16x8*)&bsrc[xoff(ni * 16 + l15, ks * 32 + grp * 8)];
#pragma unroll
    for (int mi = 0; mi < 4; ++mi)
#pragma unroll
      for (int ni = 0; ni < 7; ++ni)
        acc[mi][ni] = __builtin_amdgcn_mfma_f32_16x16x32_bf16(
            af[mi], bfr[ni], acc[mi][ni], 0, 0, 0);
  }

  // epilogue stores
  if (wave < 2) {
#pragma unroll
    for (int mi = 0; mi < 4; ++mi) {
#pragma unroll
      for (int ni = 0; ni < 7; ++ni) {
        int pos = ni * 16 + l15;
        if (pos < 100) {
#pragma unroll
          for (int r = 0; r < 4; ++r) {
            int c = wave * 64 + mi * 16 + grp * 4 + r;
            resb[((long long)(b * COUT + c)) * TV + p0 + pos] = f2bf(acc[mi][ni][r]);
          }
        }
      }
    }
  } else {
#pragma unroll
    for (int mi = 0; mi < 4; ++mi) {
      int o0 = (wave - 2) * 64 + mi * 16 + grp * 4;
#pragma unroll
      for (int ni = 0; ni < 7; ++ni) {
        int pos = ni * 16 + l15;
        if (pos < 100) {
          us4 pk;
#pragma unroll
          for (int r = 0; r < 4; ++r) pk[r] = f2bf(acc[mi][ni][r]);
          *(us4*)&h[((long long)(b * TV + p0 + pos)) * COUT + o0] = pk;
        }
      }
    }
  }

  // fused BN stats partials: per wave, 64 rows; sum over (ni, l15) valid pos.
  {
    float2* pw = &part_rs[(((long long)(blockIdx.y * 75 + blockIdx.x)) * 4 + wave) * 64];
#pragma unroll
    for (int mi = 0; mi < 4; ++mi) {
#pragma unroll
      for (int r = 0; r < 4; ++r) {
        float s = 0.f, q = 0.f;
#pragma unroll
        for (int ni = 0; ni < 7; ++ni) {
          float v = (ni < 6 || l15 < 4) ? acc[mi][ni][r] : 0.f;  // pos<100
          s += v; q += v * v;
        }
#pragma unroll
        for (int m = 1; m < 16; m <<= 1) {
          s += __shfl_xor(s, m);
          q += __shfl_xor(q, m);
        }
        if (l15 == 0) pw[mi * 16 + grp * 4 + r] = make_float2(s, q);
      }
    }
  }
}

// ---------------------------------------------------------------------------
// kC2v2: finalize res & sp BN from kA4 partials. grid 256 (stacked row).
// scales: [0]=sc_r [128]=sh_r [256]=sc_s [384]=sh_s [512]=sc_t [640]=sh_t
// ---------------------------------------------------------------------------
__global__ __launch_bounds__(256) void kC2v2(
    const float2* __restrict__ part_rs,
    const float* __restrict__ g_r,  const float* __restrict__ be_r,
    const float* __restrict__ g_sp, const float* __restrict__ be_sp,
    float* __restrict__ scales)
{
  __shared__ float rs[256], rq[256];
  const int row = blockIdx.x;          // 0..255
  const int wave = row >> 6, local = row & 63;
  const int tid = threadIdx.x;
  float s = 0.f, q = 0.f;
  for (int bid = tid; bid < 2400; bid += 256) {
    float2 v = part_rs[((long long)bid * 4 + wave) * 64 + local];
    s += v.x; q += v.y;
  }
  rs[tid] = s; rq[tid] = q;
  __syncthreads();
  for (int st = 128; st > 0; st >>= 1) {
    if (tid < st) { rs[tid] += rs[tid + st]; rq[tid] += rq[tid + st]; }
    __syncthreads();
  }
  if (tid == 0) {
    const float n = (float)NPC;
    float m = rs[0] / n, var = rq[0] / n - m * m;
    float iv = rsqrtf(var + 1e-5f);
    if (row < 128) {
      float sc = g_r[row] * iv;
      scales[row] = sc; scales[128 + row] = be_r[row] - m * sc;
    } else {
      int c = row - 128;
      float sc = g_sp[c] * iv;
      scales[256 + c] = sc; scales[384 + c] = be_sp[c] - m * sc;
    }
  }
}

// ---------------------------------------------------------------------------
// kE5: temporal conv 9x1, implicit MFMA GEMM. T14 async-stage split:
// chunk-1 global loads issued before chunk-0's MFMA phase (reg-held),
// transformed+written after. STAGE padded to 352 (11 uniform us8 iters).
// Fused BN_t stats partials. grid (59, 32), 4 waves.
// ---------------------------------------------------------------------------
constexpr int NP     = 128;
constexpr int HALO   = 100;              // 4*25
constexpr int STAGE0 = NP + 2 * HALO;    // 328 real rows
constexpr int STAGEP = 352;              // padded (352*8 = 11*256)

__global__ __launch_bounds__(256, 2) void kE5(
    const unsigned short* __restrict__ h, const unsigned short* __restrict__ wb2,
    const float* __restrict__ scales, unsigned short* __restrict__ cvb,
    float2* __restrict__ part_t)
{
  __shared__ unsigned short hs[STAGEP * 64];   // 45056 B
  const int tid  = threadIdx.x;
  const int lane = tid & 63;
  const int wave = tid >> 6;
  const int wm   = wave >> 1, wn = wave & 1;
  const int b    = blockIdx.y;
  const int p0   = blockIdx.x * NP;
  const int grp  = lane >> 4;
  const int l15  = lane & 15;
  const int slot = tid & 7;
  const us8 zero8 = (us8)(unsigned short)0;

  f32x4 acc[4][4];
#pragma unroll
  for (int m = 0; m < 4; ++m)
#pragma unroll
    for (int n = 0; n < 4; ++n) acc[m][n] = (f32x4)0.f;

  auto mfma_phase = [&](int cc) {
    __builtin_amdgcn_s_setprio(1);
    for (int k = 0; k < 9; ++k) {
      const int plb = HALO + wn * 64 + 25 * (k - 4) + l15;
#pragma unroll
      for (int ks = 0; ks < 2; ++ks) {
        bf16x8 af[4], bfr[4];
#pragma unroll
        for (int mi = 0; mi < 4; ++mi) {
          int o = wm * 64 + mi * 16 + l15;
          af[mi] = *(const bf16x8*)&wb2[((k * 16 + cc * 8 + ks * 4 + grp) * 128 + o) * 8];
        }
#pragma unroll
        for (int ni = 0; ni < 4; ++ni) {
          int pl = plb + ni * 16;
          int si = (pl << 6) + (((ks * 4 + grp) ^ (pl & 7)) << 3);
          bfr[ni] = *(const bf16x8*)&hs[si];
        }
#pragma unroll
        for (int mi = 0; mi < 4; ++mi)
#pragma unroll
          for (int ni = 0; ni < 4; ++ni)
            acc[mi][ni] = __builtin_amdgcn_mfma_f32_16x16x32_bf16(
                af[mi], bfr[ni], acc[mi][ni], 0, 0, 0);
      }
    }
    __builtin_amdgcn_s_setprio(0);
  };

  // ---- chunk 0: direct stage (c0 = 0)
  {
    float sc[8], sh[8];
#pragma unroll
    for (int e = 0; e < 8; ++e) {
      sc[e] = scales[256 + slot * 8 + e];
      sh[e] = scales[384 + slot * 8 + e];
    }
#pragma unroll
    for (int j = 0; j < 11; ++j) {
      int i = tid + j * 256;
      int pos = i >> 3;
      int pg = p0 - HALO + pos;
      us8 o = zero8;
      if (pg >= 0 && pg < TV && pos < STAGE0) {
        us8 v = *(const us8*)&h[((long long)b * TV + pg) * COUT + slot * 8];
#pragma unroll
        for (int e = 0; e < 8; ++e)
          o[e] = f2bf(fmaxf(bf2f(v[e]) * sc[e] + sh[e], 0.f));
      }
      int si = (pos << 6) + ((slot ^ (pos & 7)) << 3);
      *(us8*)&hs[si] = o;
    }
  }
  __syncthreads();

  // ---- prefetch chunk 1 (c0 = 64) into registers
  us8 pre[11];
#pragma unroll
  for (int j = 0; j < 11; ++j) {
    int i = tid + j * 256;
    int pos = i >> 3;
    int pg = p0 - HALO + pos;
    pre[j] = zero8;
    if (pg >= 0 && pg < TV && pos < STAGE0)
      pre[j] = *(const us8*)&h[((long long)b * TV + pg) * COUT + 64 + slot * 8];
  }

  mfma_phase(0);
  __syncthreads();

  // ---- chunk 1: transform + write from registers
  {
    float sc[8], sh[8];
#pragma unroll
    for (int e = 0; e < 8; ++e) {
      sc[e] = scales[256 + 64 + slot * 8 + e];
      sh[e] = scales[384 + 64 + slot * 8 + e];
    }
#pragma unroll
    for (int j = 0; j < 11; ++j) {
      int i = tid + j * 256;
      int pos = i >> 3;
      int pg = p0 - HALO + pos;
      us8 o = zero8;
      if (pg >= 0 && pg < TV && pos < STAGE0) {
#pragma unroll
        for (int e = 0; e < 8; ++e)
          o[e] = f2bf(fmaxf(bf2f(pre[j][e]) * sc[e] + sh[e], 0.f));
      }
      int si = (pos << 6) + ((slot ^ (pos & 7)) << 3);
      *(us8*)&hs[si] = o;
    }
  }
  __syncthreads();

  mfma_phase(1);

  // ---- epilogue: conv -> cvb bf16
#pragma unroll
  for (int mi = 0; mi < 4; ++mi) {
#pragma unroll
    for (int ni = 0; ni < 4; ++ni) {
      int pos = p0 + wn * 64 + ni * 16 + l15;
      if (pos < TV) {
#pragma unroll
        for (int r = 0; r < 4; ++r) {
          int o = wm * 64 + mi * 16 + grp * 4 + r;
          cvb[((long long)(b * COUT + o)) * TV + pos] = f2bf(acc[mi][ni][r]);
        }
      }
    }
  }

  // ---- fused BN_t stats partials
  {
    float2* pw = &part_t[(((long long)(blockIdx.y * 59 + blockIdx.x)) * 4 + wave) * 64];
#pragma unroll
    for (int mi = 0; mi < 4; ++mi) {
#pragma unroll
      for (int r = 0; r < 4; ++r) {
        float s = 0.f, q = 0.f;
#pragma unroll
        for (int ni = 0; ni < 4; ++ni) {
          int pos = p0 + wn * 64 + ni * 16 + l15;
          float v = (pos < TV) ? acc[mi][ni][r] : 0.f;
          s += v; q += v * v;
        }
#pragma unroll
        for (int m = 1; m < 16; m <<= 1) {
          s += __shfl_xor(s, m);
          q += __shfl_xor(q, m);
        }
        if (l15 == 0) pw[mi * 16 + grp * 4 + r] = make_float2(s, q);
      }
    }
  }
}

// ---------------------------------------------------------------------------
// kG2: finalize temporal BN from kE5 partials. grid 128 (channel).
// ---------------------------------------------------------------------------
__global__ __launch_bounds__(256) void kG2(
    const float2* __restrict__ part_t,
    const float* __restrict__ g_t, const float* __restrict__ be_t,
    float* __restrict__ scales)
{
  __shared__ float rs[256], rq[256];
  const int c = blockIdx.x;            // 0..127
  const int wm = c >> 6, local = c & 63;
  const int tid = threadIdx.x;
  const int NB = 59 * 32;              // 1888
  float s = 0.f, q = 0.f;
  for (int p = tid; p < NB * 2; p += 256) {
    int bid = p >> 1, wv = p & 1;
    float2 v = part_t[((long long)bid * 4 + (wm * 2 + wv)) * 64 + local];
    s += v.x; q += v.y;
  }
  rs[tid] = s; rq[tid] = q;
  __syncthreads();
  for (int st = 128; st > 0; st >>= 1) {
    if (tid < st) { rs[tid] += rs[tid + st]; rq[tid] += rq[tid + st]; }
    __syncthreads();
  }
  if (tid == 0) {
    const float n = (float)NPC;
    float m = rs[0] / n, var = rq[0] / n - m * m;
    float sc = g_t[c] * rsqrtf(var + 1e-5f);
    scales[512 + c] = sc;
    scales[640 + c] = be_t[c] - m * sc;
  }
}

// ---------------------------------------------------------------------------
// kH: out = relu(cvb*sc_t+sh_t + resb*sc_r+sh_r). grid 4096 planes.
// ---------------------------------------------------------------------------
__global__ __launch_bounds__(256) void kH(
    const unsigned short* __restrict__ cvb, const unsigned short* __restrict__ resb,
    const float* __restrict__ scales, float* __restrict__ out)
{
  const int plane = blockIdx.x;          // b*128 + c
  const int c = plane & 127;
  const float sct = scales[512 + c], sht = scales[640 + c];
  const float scr = scales[c],       shr = scales[128 + c];
  const us4* cp = (const us4*)&cvb[(long long)plane * TV];
  const us4* rp = (const us4*)&resb[(long long)plane * TV];
  float* op = &out[(long long)plane * TV];
  for (int u = threadIdx.x; u < 1875; u += 256) {
    us4 o4 = cp[u], r4 = rp[u];
    float4 y;
    y.x = fmaxf(bf2f(o4[0]) * sct + sht + bf2f(r4[0]) * scr + shr, 0.f);
    y.y = fmaxf(bf2f(o4[1]) * sct + sht + bf2f(r4[1]) * scr + shr, 0.f);
    y.z = fmaxf(bf2f(o4[2]) * sct + sht + bf2f(r4[2]) * scr + shr, 0.f);
    y.w = fmaxf(bf2f(o4[3]) * sct + sht + bf2f(r4[3]) * scr + shr, 0.f);
    *(float4*)&op[u * 4] = y;
  }
}

// ---------------------------------------------------------------------------
extern "C" void kernel_launch(void* const* d_in, const int* in_sizes, int n_in,
                              void* d_out, int out_size, void* d_ws, size_t ws_size,
                              hipStream_t stream) {
  const float* x     = (const float*)d_in[0];
  const float* A_hat = (const float*)d_in[1];
  const float* w_sp  = (const float*)d_in[2];
  const float* g_sp  = (const float*)d_in[4];
  const float* be_sp = (const float*)d_in[5];
  const float* w_t   = (const float*)d_in[6];
  const float* g_t   = (const float*)d_in[8];
  const float* be_t  = (const float*)d_in[9];
  const float* w_r   = (const float*)d_in[10];
  const float* g_r   = (const float*)d_in[12];
  const float* be_r  = (const float*)d_in[13];
  float* out = (float*)d_out;

  // workspace carving (all offsets 16B-aligned)
  char* base = (char*)d_ws;
  unsigned short* resb = (unsigned short*)base;                        // 61.44 MB
  unsigned short* h    = (unsigned short*)(base + (size_t)TOTAL * 2);  // 61.44 MB
  unsigned short* cvb  = (unsigned short*)(base + (size_t)TOTAL * 4);  // 61.44 MB
  unsigned short* wb2  = (unsigned short*)(base + (size_t)TOTAL * 6);  // 294912 B
  unsigned short* wrs2 = wb2 + 147456;                                 // 32768 B
  unsigned short* bdt  = wrs2 + 16384;                                 // 28672 B
  float2* part_rs = (float2*)(bdt + 14336);                            // 2400*4*64 f2 = 4.92 MB
  float2* part_t  = part_rs + 2400 * 4 * 64;                           // 1888*4*64 f2 = 3.87 MB
  float*  scales  = (float*)(part_t + 1888 * 4 * 64);                  // 768 floats

  // weight / graph-matrix prep
  kWT<<<576, 256, 0, stream>>>(w_t, wb2);
  kW2<<<64,  256, 0, stream>>>(w_r, w_sp, wrs2);
  kWB<<<56,  256, 0, stream>>>(A_hat, bdt);
  // spatial front-end (stats fused)
  kA4<<<dim3(75, 32), 256, 0, stream>>>(x, bdt, wrs2, resb, h, part_rs);
  kC2v2<<<256, 256, 0, stream>>>(part_rs, g_r, be_r, g_sp, be_sp, scales);
  // temporal conv (T14 split, BN_s+ReLU in staging, stats fused)
  kE5<<<dim3(59, 32), 256, 0, stream>>>(h, wb2, scales, cvb, part_t);
  kG2<<<128, 256, 0, stream>>>(part_t, g_t, be_t, scales);
  // fused epilogue
  kH<<<4096, 256, 0, stream>>>(cvb, resb, scales, out);
}

// Round 7
// 292.400 us; speedup vs baseline: 1.0236x; 1.0236x over previous
//
#include <hip/hip_runtime.h>

// Problem constants
constexpr int B    = 32;
constexpr int CIN  = 64;
constexpr int COUT = 128;
constexpr int T    = 300;
constexpr int V    = 25;
constexpr int TV   = T * V;            // 7500
constexpr long long NPC   = (long long)B * TV;          // 240000 per channel
constexpr long long TOTAL = (long long)B * COUT * TV;   // 30,720,000

typedef short          bf16x8 __attribute__((ext_vector_type(8)));
typedef float          f32x4  __attribute__((ext_vector_type(4)));
typedef unsigned short us8    __attribute__((ext_vector_type(8)));
typedef unsigned short us4    __attribute__((ext_vector_type(4)));

static __device__ __forceinline__ unsigned short f2bf(float f) {
  union { float f; unsigned u; } x; x.f = f;
  unsigned r = x.u + 0x7FFFu + ((x.u >> 16) & 1u);   // RNE
  return (unsigned short)(r >> 16);
}
static __device__ __forceinline__ float bf2f(unsigned short u) {
  union { unsigned u; float f; } x; x.u = ((unsigned)u) << 16;
  return x.f;
}

// async global->LDS 16B (CK-style address-space casts; m03/m97 pathway)
typedef const __attribute__((address_space(1))) unsigned int cu32_as1;
typedef __attribute__((address_space(3))) unsigned int u32_as3;
static __device__ __forceinline__ void gld_lds16(const unsigned short* g,
                                                 unsigned short* l) {
  __builtin_amdgcn_global_load_lds((cu32_as1*)g, (u32_as3*)l, 16, 0, 0);
}

// swizzled offsets for kA4 LDS tiles (unchanged, verified rounds 4-6)
static __device__ __forceinline__ int xoff(int pos, int c) {      // [pos][c<64]
  return pos * 64 + ((((c >> 3)) ^ (pos & 7)) << 3) + (c & 7);
}
static __device__ __forceinline__ int soff(int c, int pw) {       // [c][pw<128]
  return c * 128 + ((((pw >> 3)) ^ (c & 7)) << 3) + (pw & 7);
}

// ---------------------------------------------------------------------------
// kWT: temporal weights -> bf16, wb2[k][cblk=c>>3][o][e=c&7]
// ---------------------------------------------------------------------------
__global__ __launch_bounds__(256) void kWT(const float* __restrict__ w_t,
                                           unsigned short* __restrict__ wb2) {
  int i = blockIdx.x * 256 + threadIdx.x;
  if (i >= COUT * 9 * COUT) return;
  int c = i & 127, ok = i >> 7;
  int k = ok % 9, o = ok / 9;
  int idx = ((k * 16 + (c >> 3)) * 128 + o) * 8 + (c & 7);
  wb2[idx] = f2bf(w_t[(o * COUT + c) * 9 + k]);
}

// ---------------------------------------------------------------------------
// kW2: stacked 1x1 weights -> bf16, wrs2[cblk][row][e]
// ---------------------------------------------------------------------------
__global__ __launch_bounds__(256) void kW2(const float* __restrict__ w_r,
                                           const float* __restrict__ w_sp,
                                           unsigned short* __restrict__ wrs2) {
  int i = blockIdx.x * 256 + threadIdx.x;
  if (i >= 256 * CIN) return;
  int c = i & 63, row = i >> 6;
  float v = (row < COUT) ? w_r[row * CIN + c] : w_sp[(row - COUT) * CIN + c];
  wrs2[((c >> 3) * 256 + row) * 8 + (c & 7)] = f2bf(v);
}

// ---------------------------------------------------------------------------
// kWB: block-diagonal graph matrix, bdt[pv][pw] (112x128 bf16)
// ---------------------------------------------------------------------------
__global__ __launch_bounds__(256) void kWB(const float* __restrict__ A_hat,
                                           unsigned short* __restrict__ bdt) {
  int i = blockIdx.x * 256 + threadIdx.x;
  if (i >= 112 * 128) return;
  int pv = i >> 7, pw = i & 127;
  float v = 0.f;
  if (pv < 100 && pw < 100 && (pv / 25) == (pw / 25))
    v = A_hat[(pv % 25) * 25 + (pw % 25)];
  bdt[i] = f2bf(v);
}

// ---------------------------------------------------------------------------
// kA4: all-MFMA spatial front-end + fused BN-stats partials. (unchanged r6)
// ---------------------------------------------------------------------------
__global__ __launch_bounds__(256, 2) void kA4(
    const float* __restrict__ x, const unsigned short* __restrict__ bdt,
    const unsigned short* __restrict__ wrs2,
    unsigned short* __restrict__ resb, unsigned short* __restrict__ h,
    float2* __restrict__ part_rs)
{
  __shared__ unsigned short xs[64 * 128];
  __shared__ unsigned short xsp[112 * 64];
  __shared__ unsigned short axsp[112 * 64];

  const int tid  = threadIdx.x;
  const int lane = tid & 63;
  const int wave = tid >> 6;
  const int b    = blockIdx.y;
  const int p0   = blockIdx.x * 100;
  const int grp  = lane >> 4;
  const int l15  = lane & 15;

  for (int u = tid; u < 16 * 128; u += 256) {
    int pos = u & 127, c4 = u >> 7;
    int c0 = c4 * 4;
    float v0 = 0.f, v1 = 0.f, v2 = 0.f, v3 = 0.f;
    if (pos < 100) {
      const float* xp = &x[(b * CIN + c0) * TV + p0 + pos];
      v0 = xp[0]; v1 = xp[TV]; v2 = xp[2 * TV]; v3 = xp[3 * TV];
    }
    unsigned short b0 = f2bf(v0), b1 = f2bf(v1), b2 = f2bf(v2), b3 = f2bf(v3);
    xs[soff(c0,     pos)] = b0;
    xs[soff(c0 + 1, pos)] = b1;
    xs[soff(c0 + 2, pos)] = b2;
    xs[soff(c0 + 3, pos)] = b3;
    if (pos < 112) {
      us4 pk = {b0, b1, b2, b3};
      *(us4*)&xsp[xoff(pos, c0)] = pk;
    }
  }
  __syncthreads();

  bf16x8 xf[4];
#pragma unroll
  for (int ks = 0; ks < 4; ++ks)
    xf[ks] = *(const bf16x8*)&xs[soff(wave * 16 + l15, ks * 32 + grp * 8)];

  {
    f32x4 macc[7];
#pragma unroll
    for (int ni = 0; ni < 7; ++ni) macc[ni] = (f32x4)0.f;
    const int kst[7] = {0, 0, 0, 0, 1, 2, 2};
    const int kcn[7] = {1, 2, 2, 3, 3, 2, 2};
#pragma unroll
    for (int ni = 0; ni < 7; ++ni) {
      for (int kk = 0; kk < kcn[ni]; ++kk) {
        int ks = kst[ni] + kk;
        bf16x8 gf = *(const bf16x8*)&bdt[(ni * 16 + l15) * 128 + ks * 32 + grp * 8];
        macc[ni] = __builtin_amdgcn_mfma_f32_16x16x32_bf16(xf[ks], gf, macc[ni], 0, 0, 0);
      }
    }
#pragma unroll
    for (int ni = 0; ni < 7; ++ni) {
#pragma unroll
      for (int r = 0; r < 4; ++r)
        axsp[xoff(ni * 16 + l15, wave * 16 + grp * 4 + r)] = f2bf(macc[ni][r]);
    }
  }
  __syncthreads();

  const unsigned short* bsrc = (wave < 2) ? xsp : axsp;
  f32x4 acc[4][7];
#pragma unroll
  for (int m = 0; m < 4; ++m)
#pragma unroll
    for (int n = 0; n < 7; ++n) acc[m][n] = (f32x4)0.f;

#pragma unroll
  for (int ks = 0; ks < 2; ++ks) {
    bf16x8 af[4], bfr[7];
#pragma unroll
    for (int mi = 0; mi < 4; ++mi) {
      int row = wave * 64 + mi * 16 + l15;
      af[mi] = *(const bf16x8*)&wrs2[((ks * 4 + grp) * 256 + row) * 8];
    }
#pragma unroll
    for (int ni = 0; ni < 7; ++ni)
      bfr[ni] = *(const bf16x8*)&bsrc[xoff(ni * 16 + l15, ks * 32 + grp * 8)];
#pragma unroll
    for (int mi = 0; mi < 4; ++mi)
#pragma unroll
      for (int ni = 0; ni < 7; ++ni)
        acc[mi][ni] = __builtin_amdgcn_mfma_f32_16x16x32_bf16(
            af[mi], bfr[ni], acc[mi][ni], 0, 0, 0);
  }

  if (wave < 2) {
#pragma unroll
    for (int mi = 0; mi < 4; ++mi) {
#pragma unroll
      for (int ni = 0; ni < 7; ++ni) {
        int pos = ni * 16 + l15;
        if (pos < 100) {
#pragma unroll
          for (int r = 0; r < 4; ++r) {
            int c = wave * 64 + mi * 16 + grp * 4 + r;
            resb[((long long)(b * COUT + c)) * TV + p0 + pos] = f2bf(acc[mi][ni][r]);
          }
        }
      }
    }
  } else {
#pragma unroll
    for (int mi = 0; mi < 4; ++mi) {
      int o0 = (wave - 2) * 64 + mi * 16 + grp * 4;
#pragma unroll
      for (int ni = 0; ni < 7; ++ni) {
        int pos = ni * 16 + l15;
        if (pos < 100) {
          us4 pk;
#pragma unroll
          for (int r = 0; r < 4; ++r) pk[r] = f2bf(acc[mi][ni][r]);
          *(us4*)&h[((long long)(b * TV + p0 + pos)) * COUT + o0] = pk;
        }
      }
    }
  }

  {
    float2* pw = &part_rs[(((long long)(blockIdx.y * 75 + blockIdx.x)) * 4 + wave) * 64];
#pragma unroll
    for (int mi = 0; mi < 4; ++mi) {
#pragma unroll
      for (int r = 0; r < 4; ++r) {
        float s = 0.f, q = 0.f;
#pragma unroll
        for (int ni = 0; ni < 7; ++ni) {
          float v = (ni < 6 || l15 < 4) ? acc[mi][ni][r] : 0.f;
          s += v; q += v * v;
        }
#pragma unroll
        for (int m = 1; m < 16; m <<= 1) {
          s += __shfl_xor(s, m);
          q += __shfl_xor(q, m);
        }
        if (l15 == 0) pw[mi * 16 + grp * 4 + r] = make_float2(s, q);
      }
    }
  }
}

// ---------------------------------------------------------------------------
// kC2v2: finalize res & sp BN from kA4 partials. (unchanged r6)
// ---------------------------------------------------------------------------
__global__ __launch_bounds__(256) void kC2v2(
    const float2* __restrict__ part_rs,
    const float* __restrict__ g_r,  const float* __restrict__ be_r,
    const float* __restrict__ g_sp, const float* __restrict__ be_sp,
    float* __restrict__ scales)
{
  __shared__ float rs[256], rq[256];
  const int row = blockIdx.x;
  const int wave = row >> 6, local = row & 63;
  const int tid = threadIdx.x;
  float s = 0.f, q = 0.f;
  for (int bid = tid; bid < 2400; bid += 256) {
    float2 v = part_rs[((long long)bid * 4 + wave) * 64 + local];
    s += v.x; q += v.y;
  }
  rs[tid] = s; rq[tid] = q;
  __syncthreads();
  for (int st = 128; st > 0; st >>= 1) {
    if (tid < st) { rs[tid] += rs[tid + st]; rq[tid] += rq[tid + st]; }
    __syncthreads();
  }
  if (tid == 0) {
    const float n = (float)NPC;
    float m = rs[0] / n, var = rq[0] / n - m * m;
    float iv = rsqrtf(var + 1e-5f);
    if (row < 128) {
      float sc = g_r[row] * iv;
      scales[row] = sc; scales[128 + row] = be_r[row] - m * sc;
    } else {
      int c = row - 128;
      float sc = g_sp[c] * iv;
      scales[256 + c] = sc; scales[384 + c] = be_sp[c] - m * sc;
    }
  }
}

// ---------------------------------------------------------------------------
// kP: BN_s + ReLU transform h -> h4, channel-split padded planes.
// h4 layout: [b][cc(4)][RPLANE rows][32c], rows [112,112+TV) valid, pads zero.
// grid 15680 x 256: unit = ((b*RPLANE + R)*16 + cc*4 + q)
// ---------------------------------------------------------------------------
constexpr int RPLANE = 7840;
constexpr int PAD0   = 112;

__global__ __launch_bounds__(256) void kP(const unsigned short* __restrict__ h,
                                          const float* __restrict__ scales,
                                          unsigned short* __restrict__ h4) {
  int u = blockIdx.x * 256 + threadIdx.x;
  int cq = u & 15;
  int q = cq & 3, cc = cq >> 2;
  int t = u >> 4;
  int R = t % RPLANE, b = t / RPLANE;
  int c0 = cc * 32 + q * 8;
  us8 o = (us8)(unsigned short)0;
  if (R >= PAD0 && R < PAD0 + TV) {
    int pos = R - PAD0;
    us8 v = *(const us8*)&h[((long long)(b * TV + pos)) * COUT + c0];
    float4 sa = *(const float4*)&scales[256 + c0];
    float4 sb = *(const float4*)&scales[256 + c0 + 4];
    float4 ha = *(const float4*)&scales[384 + c0];
    float4 hb = *(const float4*)&scales[384 + c0 + 4];
    float sc[8] = {sa.x, sa.y, sa.z, sa.w, sb.x, sb.y, sb.z, sb.w};
    float sh[8] = {ha.x, ha.y, ha.z, ha.w, hb.x, hb.y, hb.z, hb.w};
#pragma unroll
    for (int e = 0; e < 8; ++e)
      o[e] = f2bf(fmaxf(bf2f(v[e]) * sc[e] + sh[e], 0.f));
  }
  *(us8*)&h4[(((long long)(b * 4 + cc)) * RPLANE + R) * 32 + q * 8] = o;
}

// ---------------------------------------------------------------------------
// kE6: temporal conv 9x1, implicit MFMA GEMM. 4 x 32-c K-chunks, LDS
// double-buffered, staging via global_load_lds (zero VALU / zero VGPR),
// chunk cc+1 DMA issued before chunk cc's MFMA phase (2-phase pipeline).
// Fused BN_t stats. grid (59, 32), 4 waves, 48 KB LDS, 3 blocks/CU.
// ---------------------------------------------------------------------------
constexpr int NP    = 128;
constexpr int HALO  = 100;               // 4*25
constexpr int SROWS = 384;               // 328 used, padded to 24 blk16

__global__ __launch_bounds__(256, 3) void kE6(
    const unsigned short* __restrict__ h4, const unsigned short* __restrict__ wb2,
    unsigned short* __restrict__ cvb, float2* __restrict__ part_t)
{
  __shared__ unsigned short hs[2][SROWS * 32];   // 2 x 24 KB
  const int tid  = threadIdx.x;
  const int lane = tid & 63;
  const int wave = tid >> 6;
  const int wm   = wave >> 1, wn = wave & 1;
  const int b    = blockIdx.y;
  const int p0   = blockIdx.x * NP;
  const int grp  = lane >> 4;
  const int l15  = lane & 15;

  f32x4 acc[4][4];
#pragma unroll
  for (int m = 0; m < 4; ++m)
#pragma unroll
    for (int n = 0; n < 4; ++n) acc[m][n] = (f32x4)0.f;

  // stage chunk cc into buffer buf: 6 x 1KB contiguous DMA issues per wave
  auto stage = [&](int buf, int cc) {
    const unsigned short* gb =
        &h4[(((long long)(b * 4 + cc)) * RPLANE + (p0 + 12)) * 32];
#pragma unroll
    for (int j = 0; j < 6; ++j) {
      int blk16 = j * 4 + wave;                 // 16-row block
      const unsigned short* g = gb + blk16 * 512 + lane * 8;
      unsigned short* l = &hs[buf][blk16 * 512];  // wave-uniform base
      gld_lds16(g, l);
    }
  };

  auto mfma_phase = [&](int cc, int buf) {
    const unsigned short* hb = &hs[buf][0];
    for (int k = 0; k < 9; ++k) {
      bf16x8 af[4], bfr[4];
#pragma unroll
      for (int mi = 0; mi < 4; ++mi) {
        int o = wm * 64 + mi * 16 + l15;
        af[mi] = *(const bf16x8*)&wb2[((k * 16 + cc * 4 + grp) * 128 + o) * 8];
      }
      const int plb = HALO + wn * 64 + 25 * (k - 4) + l15;
#pragma unroll
      for (int ni = 0; ni < 4; ++ni) {
        int pl = plb + ni * 16;
        bfr[ni] = *(const bf16x8*)&hb[pl * 32 + grp * 8];
      }
#pragma unroll
      for (int mi = 0; mi < 4; ++mi)
#pragma unroll
        for (int ni = 0; ni < 4; ++ni)
          acc[mi][ni] = __builtin_amdgcn_mfma_f32_16x16x32_bf16(
              af[mi], bfr[ni], acc[mi][ni], 0, 0, 0);
    }
  };

  stage(0, 0);
  __syncthreads();
  for (int cc = 0; cc < 4; ++cc) {
    if (cc < 3) stage((cc + 1) & 1, cc + 1);    // DMA flies under MFMA
    __builtin_amdgcn_s_setprio(1);
    mfma_phase(cc, cc & 1);
    __builtin_amdgcn_s_setprio(0);
    __syncthreads();                            // drains DMA -> next buf ready
  }

  // epilogue: conv -> cvb bf16
#pragma unroll
  for (int mi = 0; mi < 4; ++mi) {
#pragma unroll
    for (int ni = 0; ni < 4; ++ni) {
      int pos = p0 + wn * 64 + ni * 16 + l15;
      if (pos < TV) {
#pragma unroll
        for (int r = 0; r < 4; ++r) {
          int o = wm * 64 + mi * 16 + grp * 4 + r;
          cvb[((long long)(b * COUT + o)) * TV + pos] = f2bf(acc[mi][ni][r]);
        }
      }
    }
  }

  // fused BN_t stats partials
  {
    float2* pw = &part_t[(((long long)(blockIdx.y * 59 + blockIdx.x)) * 4 + wave) * 64];
#pragma unroll
    for (int mi = 0; mi < 4; ++mi) {
#pragma unroll
      for (int r = 0; r < 4; ++r) {
        float s = 0.f, q = 0.f;
#pragma unroll
        for (int ni = 0; ni < 4; ++ni) {
          int pos = p0 + wn * 64 + ni * 16 + l15;
          float v = (pos < TV) ? acc[mi][ni][r] : 0.f;
          s += v; q += v * v;
        }
#pragma unroll
        for (int m = 1; m < 16; m <<= 1) {
          s += __shfl_xor(s, m);
          q += __shfl_xor(q, m);
        }
        if (l15 == 0) pw[mi * 16 + grp * 4 + r] = make_float2(s, q);
      }
    }
  }
}

// ---------------------------------------------------------------------------
// kG2: finalize temporal BN from kE6 partials. (unchanged r6)
// ---------------------------------------------------------------------------
__global__ __launch_bounds__(256) void kG2(
    const float2* __restrict__ part_t,
    const float* __restrict__ g_t, const float* __restrict__ be_t,
    float* __restrict__ scales)
{
  __shared__ float rs[256], rq[256];
  const int c = blockIdx.x;
  const int wm = c >> 6, local = c & 63;
  const int tid = threadIdx.x;
  const int NB = 59 * 32;
  float s = 0.f, q = 0.f;
  for (int p = tid; p < NB * 2; p += 256) {
    int bid = p >> 1, wv = p & 1;
    float2 v = part_t[((long long)bid * 4 + (wm * 2 + wv)) * 64 + local];
    s += v.x; q += v.y;
  }
  rs[tid] = s; rq[tid] = q;
  __syncthreads();
  for (int st = 128; st > 0; st >>= 1) {
    if (tid < st) { rs[tid] += rs[tid + st]; rq[tid] += rq[tid + st]; }
    __syncthreads();
  }
  if (tid == 0) {
    const float n = (float)NPC;
    float m = rs[0] / n, var = rq[0] / n - m * m;
    float sc = g_t[c] * rsqrtf(var + 1e-5f);
    scales[512 + c] = sc;
    scales[640 + c] = be_t[c] - m * sc;
  }
}

// ---------------------------------------------------------------------------
// kH: out = relu(cvb*sc_t+sh_t + resb*sc_r+sh_r). (unchanged r6)
// ---------------------------------------------------------------------------
__global__ __launch_bounds__(256) void kH(
    const unsigned short* __restrict__ cvb, const unsigned short* __restrict__ resb,
    const float* __restrict__ scales, float* __restrict__ out)
{
  const int plane = blockIdx.x;
  const int c = plane & 127;
  const float sct = scales[512 + c], sht = scales[640 + c];
  const float scr = scales[c],       shr = scales[128 + c];
  const us4* cp = (const us4*)&cvb[(long long)plane * TV];
  const us4* rp = (const us4*)&resb[(long long)plane * TV];
  float* op = &out[(long long)plane * TV];
  for (int u = threadIdx.x; u < 1875; u += 256) {
    us4 o4 = cp[u], r4 = rp[u];
    float4 y;
    y.x = fmaxf(bf2f(o4[0]) * sct + sht + bf2f(r4[0]) * scr + shr, 0.f);
    y.y = fmaxf(bf2f(o4[1]) * sct + sht + bf2f(r4[1]) * scr + shr, 0.f);
    y.z = fmaxf(bf2f(o4[2]) * sct + sht + bf2f(r4[2]) * scr + shr, 0.f);
    y.w = fmaxf(bf2f(o4[3]) * sct + sht + bf2f(r4[3]) * scr + shr, 0.f);
    *(float4*)&op[u * 4] = y;
  }
}

// ---------------------------------------------------------------------------
extern "C" void kernel_launch(void* const* d_in, const int* in_sizes, int n_in,
                              void* d_out, int out_size, void* d_ws, size_t ws_size,
                              hipStream_t stream) {
  const float* x     = (const float*)d_in[0];
  const float* A_hat = (const float*)d_in[1];
  const float* w_sp  = (const float*)d_in[2];
  const float* g_sp  = (const float*)d_in[4];
  const float* be_sp = (const float*)d_in[5];
  const float* w_t   = (const float*)d_in[6];
  const float* g_t   = (const float*)d_in[8];
  const float* be_t  = (const float*)d_in[9];
  const float* w_r   = (const float*)d_in[10];
  const float* g_r   = (const float*)d_in[12];
  const float* be_r  = (const float*)d_in[13];
  float* out = (float*)d_out;

  // workspace carving (shorts). cvb aliases h (h dead after kP).
  unsigned short* base_us = (unsigned short*)d_ws;
  unsigned short* resb = base_us;                          // TOTAL
  unsigned short* h    = base_us + (size_t)TOTAL;          // TOTAL
  unsigned short* cvb  = h;                                // alias (h dead after kP)
  unsigned short* h4   = base_us + (size_t)(2 * TOTAL);    // 32*4*7840*32 = 32,112,640
  unsigned short* wb2  = h4 + (size_t)32112640;            // 147456
  unsigned short* wrs2 = wb2 + 147456;                     // 16384
  unsigned short* bdt  = wrs2 + 16384;                     // 14336
  float2* part_rs = (float2*)(bdt + 14336);                // 2400*4*64
  float2* part_t  = part_rs + 2400 * 4 * 64;               // 1888*4*64
  float*  scales  = (float*)(part_t + 1888 * 4 * 64);      // 768 floats

  // weight / graph-matrix prep
  kWT<<<576, 256, 0, stream>>>(w_t, wb2);
  kW2<<<64,  256, 0, stream>>>(w_r, w_sp, wrs2);
  kWB<<<56,  256, 0, stream>>>(A_hat, bdt);
  // spatial front-end (stats fused)
  kA4<<<dim3(75, 32), 256, 0, stream>>>(x, bdt, wrs2, resb, h, part_rs);
  kC2v2<<<256, 256, 0, stream>>>(part_rs, g_r, be_r, g_sp, be_sp, scales);
  // BN_s+ReLU pre-transform into padded split planes
  kP<<<15680, 256, 0, stream>>>(h, scales, h4);
  // temporal conv (DMA-staged, double-buffered, stats fused)
  kE6<<<dim3(59, 32), 256, 0, stream>>>(h4, wb2, cvb, part_t);
  kG2<<<128, 256, 0, stream>>>(part_t, g_t, be_t, scales);
  // fused epilogue
  kH<<<4096, 256, 0, stream>>>(cvb, resb, scales, out);
}

// Round 8
// 276.360 us; speedup vs baseline: 1.0830x; 1.0580x over previous
//
#include <hip/hip_runtime.h>

// Problem constants
constexpr int B    = 32;
constexpr int CIN  = 64;
constexpr int COUT = 128;
constexpr int T    = 300;
constexpr int V    = 25;
constexpr int TV   = T * V;            // 7500
constexpr long long NPC   = (long long)B * TV;          // 240000 per channel
constexpr long long TOTAL = (long long)B * COUT * TV;   // 30,720,000

typedef short          bf16x8 __attribute__((ext_vector_type(8)));
typedef float          f32x4  __attribute__((ext_vector_type(4)));
typedef unsigned short us8    __attribute__((ext_vector_type(8)));
typedef unsigned short us4    __attribute__((ext_vector_type(4)));

static __device__ __forceinline__ unsigned short f2bf(float f) {
  union { float f; unsigned u; } x; x.f = f;
  unsigned r = x.u + 0x7FFFu + ((x.u >> 16) & 1u);   // RNE
  return (unsigned short)(r >> 16);
}
static __device__ __forceinline__ float bf2f(unsigned short u) {
  union { unsigned u; float f; } x; x.u = ((unsigned)u) << 16;
  return x.f;
}

// swizzled offsets for kA4 LDS tiles (verified rounds 4-7)
static __device__ __forceinline__ int xoff(int pos, int c) {      // [pos][c<64]
  return pos * 64 + ((((c >> 3)) ^ (pos & 7)) << 3) + (c & 7);
}
static __device__ __forceinline__ int soff(int c, int pw) {       // [c][pw<128]
  return c * 128 + ((((pw >> 3)) ^ (c & 7)) << 3) + (pw & 7);
}

// ---------------------------------------------------------------------------
// kPrep: all weight/graph-matrix prep in one launch. 696 blocks x 256.
//  [0, 147456)            : w_t -> wb2[k][cblk][o][e]
//  [147456, +16384)       : stacked 1x1 weights -> wrs2[cblk][row][e]
//  [147456+16384, +14336) : block-diag graph matrix bdt[pv][pw] 112x128
// ---------------------------------------------------------------------------
__global__ __launch_bounds__(256) void kPrep(
    const float* __restrict__ w_t, const float* __restrict__ w_r,
    const float* __restrict__ w_sp, const float* __restrict__ A_hat,
    unsigned short* __restrict__ wb2, unsigned short* __restrict__ wrs2,
    unsigned short* __restrict__ bdt)
{
  int i = blockIdx.x * 256 + threadIdx.x;
  if (i < 147456) {
    int c = i & 127, ok = i >> 7;
    int k = ok % 9, o = ok / 9;
    int idx = ((k * 16 + (c >> 3)) * 128 + o) * 8 + (c & 7);
    wb2[idx] = f2bf(w_t[(o * COUT + c) * 9 + k]);
  } else if (i < 147456 + 16384) {
    int j = i - 147456;
    int c = j & 63, row = j >> 6;
    float v = (row < COUT) ? w_r[row * CIN + c] : w_sp[(row - COUT) * CIN + c];
    wrs2[((c >> 3) * 256 + row) * 8 + (c & 7)] = f2bf(v);
  } else {
    int j = i - 147456 - 16384;   // < 14336 guaranteed by grid
    int pv = j >> 7, pw = j & 127;
    float v = 0.f;
    if (pv < 100 && pw < 100 && (pv / 25) == (pw / 25))
      v = A_hat[(pv % 25) * 25 + (pw % 25)];
    bdt[j] = f2bf(v);
  }
}

// ---------------------------------------------------------------------------
// kA4: all-MFMA spatial front-end + fused BN-stats partials.
// grid (75, 32), 4 waves, 3 blocks/CU (45KB LDS).
// ---------------------------------------------------------------------------
__global__ __launch_bounds__(256, 3) void kA4(
    const float* __restrict__ x, const unsigned short* __restrict__ bdt,
    const unsigned short* __restrict__ wrs2,
    unsigned short* __restrict__ resb, unsigned short* __restrict__ h,
    float2* __restrict__ part_rs)
{
  __shared__ unsigned short xs[64 * 128];
  __shared__ unsigned short xsp[112 * 64];
  __shared__ unsigned short axsp[112 * 64];

  const int tid  = threadIdx.x;
  const int lane = tid & 63;
  const int wave = tid >> 6;
  const int b    = blockIdx.y;
  const int p0   = blockIdx.x * 100;
  const int grp  = lane >> 4;
  const int l15  = lane & 15;

  for (int u = tid; u < 16 * 128; u += 256) {
    int pos = u & 127, c4 = u >> 7;
    int c0 = c4 * 4;
    float v0 = 0.f, v1 = 0.f, v2 = 0.f, v3 = 0.f;
    if (pos < 100) {
      const float* xp = &x[(b * CIN + c0) * TV + p0 + pos];
      v0 = xp[0]; v1 = xp[TV]; v2 = xp[2 * TV]; v3 = xp[3 * TV];
    }
    unsigned short b0 = f2bf(v0), b1 = f2bf(v1), b2 = f2bf(v2), b3 = f2bf(v3);
    xs[soff(c0,     pos)] = b0;
    xs[soff(c0 + 1, pos)] = b1;
    xs[soff(c0 + 2, pos)] = b2;
    xs[soff(c0 + 3, pos)] = b3;
    if (pos < 112) {
      us4 pk = {b0, b1, b2, b3};
      *(us4*)&xsp[xoff(pos, c0)] = pk;
    }
  }
  __syncthreads();

  bf16x8 xf[4];
#pragma unroll
  for (int ks = 0; ks < 4; ++ks)
    xf[ks] = *(const bf16x8*)&xs[soff(wave * 16 + l15, ks * 32 + grp * 8)];

  {
    f32x4 macc[7];
#pragma unroll
    for (int ni = 0; ni < 7; ++ni) macc[ni] = (f32x4)0.f;
    const int kst[7] = {0, 0, 0, 0, 1, 2, 2};
    const int kcn[7] = {1, 2, 2, 3, 3, 2, 2};
#pragma unroll
    for (int ni = 0; ni < 7; ++ni) {
      for (int kk = 0; kk < kcn[ni]; ++kk) {
        int ks = kst[ni] + kk;
        bf16x8 gf = *(const bf16x8*)&bdt[(ni * 16 + l15) * 128 + ks * 32 + grp * 8];
        macc[ni] = __builtin_amdgcn_mfma_f32_16x16x32_bf16(xf[ks], gf, macc[ni], 0, 0, 0);
      }
    }
#pragma unroll
    for (int ni = 0; ni < 7; ++ni) {
#pragma unroll
      for (int r = 0; r < 4; ++r)
        axsp[xoff(ni * 16 + l15, wave * 16 + grp * 4 + r)] = f2bf(macc[ni][r]);
    }
  }
  __syncthreads();

  const unsigned short* bsrc = (wave < 2) ? xsp : axsp;
  f32x4 acc[4][7];
#pragma unroll
  for (int m = 0; m < 4; ++m)
#pragma unroll
    for (int n = 0; n < 7; ++n) acc[m][n] = (f32x4)0.f;

#pragma unroll
  for (int ks = 0; ks < 2; ++ks) {
    bf16x8 af[4], bfr[7];
#pragma unroll
    for (int mi = 0; mi < 4; ++mi) {
      int row = wave * 64 + mi * 16 + l15;
      af[mi] = *(const bf16x8*)&wrs2[((ks * 4 + grp) * 256 + row) * 8];
    }
#pragma unroll
    for (int ni = 0; ni < 7; ++ni)
      bfr[ni] = *(const bf16x8*)&bsrc[xoff(ni * 16 + l15, ks * 32 + grp * 8)];
#pragma unroll
    for (int mi = 0; mi < 4; ++mi)
#pragma unroll
      for (int ni = 0; ni < 7; ++ni)
        acc[mi][ni] = __builtin_amdgcn_mfma_f32_16x16x32_bf16(
            af[mi], bfr[ni], acc[mi][ni], 0, 0, 0);
  }

  if (wave < 2) {
#pragma unroll
    for (int mi = 0; mi < 4; ++mi) {
#pragma unroll
      for (int ni = 0; ni < 7; ++ni) {
        int pos = ni * 16 + l15;
        if (pos < 100) {
#pragma unroll
          for (int r = 0; r < 4; ++r) {
            int c = wave * 64 + mi * 16 + grp * 4 + r;
            resb[((long long)(b * COUT + c)) * TV + p0 + pos] = f2bf(acc[mi][ni][r]);
          }
        }
      }
    }
  } else {
#pragma unroll
    for (int mi = 0; mi < 4; ++mi) {
      int o0 = (wave - 2) * 64 + mi * 16 + grp * 4;
#pragma unroll
      for (int ni = 0; ni < 7; ++ni) {
        int pos = ni * 16 + l15;
        if (pos < 100) {
          us4 pk;
#pragma unroll
          for (int r = 0; r < 4; ++r) pk[r] = f2bf(acc[mi][ni][r]);
          *(us4*)&h[((long long)(b * TV + p0 + pos)) * COUT + o0] = pk;
        }
      }
    }
  }

  {
    float2* pw = &part_rs[(((long long)(blockIdx.y * 75 + blockIdx.x)) * 4 + wave) * 64];
#pragma unroll
    for (int mi = 0; mi < 4; ++mi) {
#pragma unroll
      for (int r = 0; r < 4; ++r) {
        float s = 0.f, q = 0.f;
#pragma unroll
        for (int ni = 0; ni < 7; ++ni) {
          float v = (ni < 6 || l15 < 4) ? acc[mi][ni][r] : 0.f;
          s += v; q += v * v;
        }
#pragma unroll
        for (int m = 1; m < 16; m <<= 1) {
          s += __shfl_xor(s, m);
          q += __shfl_xor(q, m);
        }
        if (l15 == 0) pw[mi * 16 + grp * 4 + r] = make_float2(s, q);
      }
    }
  }
}

// ---------------------------------------------------------------------------
// kC2v2: finalize res & sp BN from kA4 partials. grid 256.
// scales: [0]=sc_r [128]=sh_r [256]=sc_s [384]=sh_s [512]=sc_t [640]=sh_t
// ---------------------------------------------------------------------------
__global__ __launch_bounds__(256) void kC2v2(
    const float2* __restrict__ part_rs,
    const float* __restrict__ g_r,  const float* __restrict__ be_r,
    const float* __restrict__ g_sp, const float* __restrict__ be_sp,
    float* __restrict__ scales)
{
  __shared__ float rs[256], rq[256];
  const int row = blockIdx.x;
  const int wave = row >> 6, local = row & 63;
  const int tid = threadIdx.x;
  float s = 0.f, q = 0.f;
  for (int bid = tid; bid < 2400; bid += 256) {
    float2 v = part_rs[((long long)bid * 4 + wave) * 64 + local];
    s += v.x; q += v.y;
  }
  rs[tid] = s; rq[tid] = q;
  __syncthreads();
  for (int st = 128; st > 0; st >>= 1) {
    if (tid < st) { rs[tid] += rs[tid + st]; rq[tid] += rq[tid + st]; }
    __syncthreads();
  }
  if (tid == 0) {
    const float n = (float)NPC;
    float m = rs[0] / n, var = rq[0] / n - m * m;
    float iv = rsqrtf(var + 1e-5f);
    if (row < 128) {
      float sc = g_r[row] * iv;
      scales[row] = sc; scales[128 + row] = be_r[row] - m * sc;
    } else {
      int c = row - 128;
      float sc = g_sp[c] * iv;
      scales[256 + c] = sc; scales[384 + c] = be_sp[c] - m * sc;
    }
  }
}

// ---------------------------------------------------------------------------
// kE4R: temporal conv 9x1, implicit MFMA GEMM (round-5 kE4 structure:
// BN_s+ReLU fused into vectorized swizzled staging, 0 conflicts) + fused
// BN_t stats + setprio around MFMA. grid (59, 32), 4 waves, 3 blocks/CU.
// ---------------------------------------------------------------------------
constexpr int NP    = 128;
constexpr int HALO  = 100;               // 4*25
constexpr int STAGE = NP + 2 * HALO;     // 328

__global__ __launch_bounds__(256, 3) void kE4R(
    const unsigned short* __restrict__ h, const unsigned short* __restrict__ wb2,
    const float* __restrict__ scales, unsigned short* __restrict__ cvb,
    float2* __restrict__ part_t)
{
  __shared__ unsigned short hs[STAGE * 64];   // 41984 B
  const int tid  = threadIdx.x;
  const int lane = tid & 63;
  const int wave = tid >> 6;
  const int wm   = wave >> 1, wn = wave & 1;
  const int b    = blockIdx.y;
  const int p0   = blockIdx.x * NP;
  const int grp  = lane >> 4;
  const int l15  = lane & 15;
  const int slot = tid & 7;

  f32x4 acc[4][4];
#pragma unroll
  for (int m = 0; m < 4; ++m)
#pragma unroll
    for (int n = 0; n < 4; ++n) acc[m][n] = (f32x4)0.f;

  for (int cc = 0; cc < 2; ++cc) {
    if (cc) __syncthreads();
    const int c0 = cc * 64;
    float sc[8], sh[8];
#pragma unroll
    for (int e = 0; e < 8; ++e) {
      sc[e] = scales[256 + c0 + slot * 8 + e];
      sh[e] = scales[384 + c0 + slot * 8 + e];
    }
    for (int i = tid; i < STAGE * 8; i += 256) {
      int pos = i >> 3;
      int pg = p0 - HALO + pos;
      us8 o = (us8)(unsigned short)0;
      if (pg >= 0 && pg < TV) {
        us8 v = *(const us8*)&h[((long long)b * TV + pg) * COUT + c0 + slot * 8];
#pragma unroll
        for (int e = 0; e < 8; ++e)
          o[e] = f2bf(fmaxf(bf2f(v[e]) * sc[e] + sh[e], 0.f));
      }
      int si = (pos << 6) + ((slot ^ (pos & 7)) << 3);
      *(us8*)&hs[si] = o;
    }
    __syncthreads();

    __builtin_amdgcn_s_setprio(1);
    for (int k = 0; k < 9; ++k) {
      const int plb = HALO + wn * 64 + 25 * (k - 4) + l15;
#pragma unroll
      for (int ks = 0; ks < 2; ++ks) {
        bf16x8 af[4], bfr[4];
#pragma unroll
        for (int mi = 0; mi < 4; ++mi) {
          int o = wm * 64 + mi * 16 + l15;
          af[mi] = *(const bf16x8*)&wb2[((k * 16 + cc * 8 + ks * 4 + grp) * 128 + o) * 8];
        }
#pragma unroll
        for (int ni = 0; ni < 4; ++ni) {
          int pl = plb + ni * 16;
          int si = (pl << 6) + (((ks * 4 + grp) ^ (pl & 7)) << 3);
          bfr[ni] = *(const bf16x8*)&hs[si];
        }
#pragma unroll
        for (int mi = 0; mi < 4; ++mi)
#pragma unroll
          for (int ni = 0; ni < 4; ++ni)
            acc[mi][ni] = __builtin_amdgcn_mfma_f32_16x16x32_bf16(
                af[mi], bfr[ni], acc[mi][ni], 0, 0, 0);
      }
    }
    __builtin_amdgcn_s_setprio(0);
  }

  // epilogue: conv -> cvb bf16
#pragma unroll
  for (int mi = 0; mi < 4; ++mi) {
#pragma unroll
    for (int ni = 0; ni < 4; ++ni) {
      int pos = p0 + wn * 64 + ni * 16 + l15;
      if (pos < TV) {
#pragma unroll
        for (int r = 0; r < 4; ++r) {
          int o = wm * 64 + mi * 16 + grp * 4 + r;
          cvb[((long long)(b * COUT + o)) * TV + pos] = f2bf(acc[mi][ni][r]);
        }
      }
    }
  }

  // fused BN_t stats partials
  {
    float2* pw = &part_t[(((long long)(blockIdx.y * 59 + blockIdx.x)) * 4 + wave) * 64];
#pragma unroll
    for (int mi = 0; mi < 4; ++mi) {
#pragma unroll
      for (int r = 0; r < 4; ++r) {
        float s = 0.f, q = 0.f;
#pragma unroll
        for (int ni = 0; ni < 4; ++ni) {
          int pos = p0 + wn * 64 + ni * 16 + l15;
          float v = (pos < TV) ? acc[mi][ni][r] : 0.f;
          s += v; q += v * v;
        }
#pragma unroll
        for (int m = 1; m < 16; m <<= 1) {
          s += __shfl_xor(s, m);
          q += __shfl_xor(q, m);
        }
        if (l15 == 0) pw[mi * 16 + grp * 4 + r] = make_float2(s, q);
      }
    }
  }
}

// ---------------------------------------------------------------------------
// kG2: finalize temporal BN from kE4R partials. grid 128.
// ---------------------------------------------------------------------------
__global__ __launch_bounds__(256) void kG2(
    const float2* __restrict__ part_t,
    const float* __restrict__ g_t, const float* __restrict__ be_t,
    float* __restrict__ scales)
{
  __shared__ float rs[256], rq[256];
  const int c = blockIdx.x;
  const int wm = c >> 6, local = c & 63;
  const int tid = threadIdx.x;
  const int NB = 59 * 32;
  float s = 0.f, q = 0.f;
  for (int p = tid; p < NB * 2; p += 256) {
    int bid = p >> 1, wv = p & 1;
    float2 v = part_t[((long long)bid * 4 + (wm * 2 + wv)) * 64 + local];
    s += v.x; q += v.y;
  }
  rs[tid] = s; rq[tid] = q;
  __syncthreads();
  for (int st = 128; st > 0; st >>= 1) {
    if (tid < st) { rs[tid] += rs[tid + st]; rq[tid] += rq[tid + st]; }
    __syncthreads();
  }
  if (tid == 0) {
    const float n = (float)NPC;
    float m = rs[0] / n, var = rq[0] / n - m * m;
    float sc = g_t[c] * rsqrtf(var + 1e-5f);
    scales[512 + c] = sc;
    scales[640 + c] = be_t[c] - m * sc;
  }
}

// ---------------------------------------------------------------------------
// kH: out = relu(cvb*sc_t+sh_t + resb*sc_r+sh_r). grid 4096 planes.
// ---------------------------------------------------------------------------
__global__ __launch_bounds__(256) void kH(
    const unsigned short* __restrict__ cvb, const unsigned short* __restrict__ resb,
    const float* __restrict__ scales, float* __restrict__ out)
{
  const int plane = blockIdx.x;
  const int c = plane & 127;
  const float sct = scales[512 + c], sht = scales[640 + c];
  const float scr = scales[c],       shr = scales[128 + c];
  const us4* cp = (const us4*)&cvb[(long long)plane * TV];
  const us4* rp = (const us4*)&resb[(long long)plane * TV];
  float* op = &out[(long long)plane * TV];
  for (int u = threadIdx.x; u < 1875; u += 256) {
    us4 o4 = cp[u], r4 = rp[u];
    float4 y;
    y.x = fmaxf(bf2f(o4[0]) * sct + sht + bf2f(r4[0]) * scr + shr, 0.f);
    y.y = fmaxf(bf2f(o4[1]) * sct + sht + bf2f(r4[1]) * scr + shr, 0.f);
    y.z = fmaxf(bf2f(o4[2]) * sct + sht + bf2f(r4[2]) * scr + shr, 0.f);
    y.w = fmaxf(bf2f(o4[3]) * sct + sht + bf2f(r4[3]) * scr + shr, 0.f);
    *(float4*)&op[u * 4] = y;
  }
}

// ---------------------------------------------------------------------------
extern "C" void kernel_launch(void* const* d_in, const int* in_sizes, int n_in,
                              void* d_out, int out_size, void* d_ws, size_t ws_size,
                              hipStream_t stream) {
  const float* x     = (const float*)d_in[0];
  const float* A_hat = (const float*)d_in[1];
  const float* w_sp  = (const float*)d_in[2];
  const float* g_sp  = (const float*)d_in[4];
  const float* be_sp = (const float*)d_in[5];
  const float* w_t   = (const float*)d_in[6];
  const float* g_t   = (const float*)d_in[8];
  const float* be_t  = (const float*)d_in[9];
  const float* w_r   = (const float*)d_in[10];
  const float* g_r   = (const float*)d_in[12];
  const float* be_r  = (const float*)d_in[13];
  float* out = (float*)d_out;

  // workspace carving (shorts)
  unsigned short* base_us = (unsigned short*)d_ws;
  unsigned short* resb = base_us;                          // TOTAL
  unsigned short* h    = base_us + (size_t)TOTAL;          // TOTAL
  unsigned short* cvb  = base_us + (size_t)(2 * TOTAL);    // TOTAL
  unsigned short* wb2  = base_us + (size_t)(3 * TOTAL);    // 147456
  unsigned short* wrs2 = wb2 + 147456;                     // 16384
  unsigned short* bdt  = wrs2 + 16384;                     // 14336
  float2* part_rs = (float2*)(bdt + 14336);                // 2400*4*64
  float2* part_t  = part_rs + 2400 * 4 * 64;               // 1888*4*64
  float*  scales  = (float*)(part_t + 1888 * 4 * 64);      // 768 floats

  // all prep in one launch
  kPrep<<<696, 256, 0, stream>>>(w_t, w_r, w_sp, A_hat, wb2, wrs2, bdt);
  // spatial front-end (stats fused)
  kA4<<<dim3(75, 32), 256, 0, stream>>>(x, bdt, wrs2, resb, h, part_rs);
  kC2v2<<<256, 256, 0, stream>>>(part_rs, g_r, be_r, g_sp, be_sp, scales);
  // temporal conv (fused BN_s+ReLU staging, swizzled, stats fused)
  kE4R<<<dim3(59, 32), 256, 0, stream>>>(h, wb2, scales, cvb, part_t);
  kG2<<<128, 256, 0, stream>>>(part_t, g_t, be_t, scales);
  // fused epilogue
  kH<<<4096, 256, 0, stream>>>(cvb, resb, scales, out);
}

// Round 9
// 249.890 us; speedup vs baseline: 1.1977x; 1.1059x over previous
//
#include <hip/hip_runtime.h>

// Problem constants
constexpr int B    = 32;
constexpr int CIN  = 64;
constexpr int COUT = 128;
constexpr int T    = 300;
constexpr int V    = 25;
constexpr int TV   = T * V;            // 7500
constexpr long long NPC   = (long long)B * TV;          // 240000 per channel
constexpr long long TOTAL = (long long)B * COUT * TV;   // 30,720,000

typedef short          bf16x8 __attribute__((ext_vector_type(8)));
typedef float          f32x4  __attribute__((ext_vector_type(4)));
typedef unsigned short us8    __attribute__((ext_vector_type(8)));
typedef unsigned short us4    __attribute__((ext_vector_type(4)));

static __device__ __forceinline__ unsigned short f2bf(float f) {
  union { float f; unsigned u; } x; x.f = f;
  unsigned r = x.u + 0x7FFFu + ((x.u >> 16) & 1u);   // RNE
  return (unsigned short)(r >> 16);
}
static __device__ __forceinline__ float bf2f(unsigned short u) {
  union { unsigned u; float f; } x; x.u = ((unsigned)u) << 16;
  return x.f;
}

// swizzled offsets for kA4 LDS tiles (verified rounds 4-8)
static __device__ __forceinline__ int xoff(int pos, int c) {      // [pos][c<64]
  return pos * 64 + ((((c >> 3)) ^ (pos & 7)) << 3) + (c & 7);
}
static __device__ __forceinline__ int soff(int c, int pw) {       // [c][pw<128]
  return c * 128 + ((((pw >> 3)) ^ (c & 7)) << 3) + (pw & 7);
}

// ---------------------------------------------------------------------------
// kPrep: all weight/graph-matrix prep in one launch. 696 blocks x 256.
// ---------------------------------------------------------------------------
__global__ __launch_bounds__(256) void kPrep(
    const float* __restrict__ w_t, const float* __restrict__ w_r,
    const float* __restrict__ w_sp, const float* __restrict__ A_hat,
    unsigned short* __restrict__ wb2, unsigned short* __restrict__ wrs2,
    unsigned short* __restrict__ bdt)
{
  int i = blockIdx.x * 256 + threadIdx.x;
  if (i < 147456) {
    int c = i & 127, ok = i >> 7;
    int k = ok % 9, o = ok / 9;
    int idx = ((k * 16 + (c >> 3)) * 128 + o) * 8 + (c & 7);
    wb2[idx] = f2bf(w_t[(o * COUT + c) * 9 + k]);
  } else if (i < 147456 + 16384) {
    int j = i - 147456;
    int c = j & 63, row = j >> 6;
    float v = (row < COUT) ? w_r[row * CIN + c] : w_sp[(row - COUT) * CIN + c];
    wrs2[((c >> 3) * 256 + row) * 8 + (c & 7)] = f2bf(v);
  } else {
    int j = i - 147456 - 16384;
    int pv = j >> 7, pw = j & 127;
    float v = 0.f;
    if (pv < 100 && pw < 100 && (pv / 25) == (pw / 25))
      v = A_hat[(pv % 25) * 25 + (pw % 25)];
    bdt[j] = f2bf(v);
  }
}

// ---------------------------------------------------------------------------
// kA4: all-MFMA spatial front-end + fused BN-stats partials. (unchanged r8)
// ---------------------------------------------------------------------------
__global__ __launch_bounds__(256, 3) void kA4(
    const float* __restrict__ x, const unsigned short* __restrict__ bdt,
    const unsigned short* __restrict__ wrs2,
    unsigned short* __restrict__ resb, unsigned short* __restrict__ h,
    float2* __restrict__ part_rs)
{
  __shared__ unsigned short xs[64 * 128];
  __shared__ unsigned short xsp[112 * 64];
  __shared__ unsigned short axsp[112 * 64];

  const int tid  = threadIdx.x;
  const int lane = tid & 63;
  const int wave = tid >> 6;
  const int b    = blockIdx.y;
  const int p0   = blockIdx.x * 100;
  const int grp  = lane >> 4;
  const int l15  = lane & 15;

  for (int u = tid; u < 16 * 128; u += 256) {
    int pos = u & 127, c4 = u >> 7;
    int c0 = c4 * 4;
    float v0 = 0.f, v1 = 0.f, v2 = 0.f, v3 = 0.f;
    if (pos < 100) {
      const float* xp = &x[(b * CIN + c0) * TV + p0 + pos];
      v0 = xp[0]; v1 = xp[TV]; v2 = xp[2 * TV]; v3 = xp[3 * TV];
    }
    unsigned short b0 = f2bf(v0), b1 = f2bf(v1), b2 = f2bf(v2), b3 = f2bf(v3);
    xs[soff(c0,     pos)] = b0;
    xs[soff(c0 + 1, pos)] = b1;
    xs[soff(c0 + 2, pos)] = b2;
    xs[soff(c0 + 3, pos)] = b3;
    if (pos < 112) {
      us4 pk = {b0, b1, b2, b3};
      *(us4*)&xsp[xoff(pos, c0)] = pk;
    }
  }
  __syncthreads();

  bf16x8 xf[4];
#pragma unroll
  for (int ks = 0; ks < 4; ++ks)
    xf[ks] = *(const bf16x8*)&xs[soff(wave * 16 + l15, ks * 32 + grp * 8)];

  {
    f32x4 macc[7];
#pragma unroll
    for (int ni = 0; ni < 7; ++ni) macc[ni] = (f32x4)0.f;
    const int kst[7] = {0, 0, 0, 0, 1, 2, 2};
    const int kcn[7] = {1, 2, 2, 3, 3, 2, 2};
#pragma unroll
    for (int ni = 0; ni < 7; ++ni) {
      for (int kk = 0; kk < kcn[ni]; ++kk) {
        int ks = kst[ni] + kk;
        bf16x8 gf = *(const bf16x8*)&bdt[(ni * 16 + l15) * 128 + ks * 32 + grp * 8];
        macc[ni] = __builtin_amdgcn_mfma_f32_16x16x32_bf16(xf[ks], gf, macc[ni], 0, 0, 0);
      }
    }
#pragma unroll
    for (int ni = 0; ni < 7; ++ni) {
#pragma unroll
      for (int r = 0; r < 4; ++r)
        axsp[xoff(ni * 16 + l15, wave * 16 + grp * 4 + r)] = f2bf(macc[ni][r]);
    }
  }
  __syncthreads();

  const unsigned short* bsrc = (wave < 2) ? xsp : axsp;
  f32x4 acc[4][7];
#pragma unroll
  for (int m = 0; m < 4; ++m)
#pragma unroll
    for (int n = 0; n < 7; ++n) acc[m][n] = (f32x4)0.f;

#pragma unroll
  for (int ks = 0; ks < 2; ++ks) {
    bf16x8 af[4], bfr[7];
#pragma unroll
    for (int mi = 0; mi < 4; ++mi) {
      int row = wave * 64 + mi * 16 + l15;
      af[mi] = *(const bf16x8*)&wrs2[((ks * 4 + grp) * 256 + row) * 8];
    }
#pragma unroll
    for (int ni = 0; ni < 7; ++ni)
      bfr[ni] = *(const bf16x8*)&bsrc[xoff(ni * 16 + l15, ks * 32 + grp * 8)];
#pragma unroll
    for (int mi = 0; mi < 4; ++mi)
#pragma unroll
      for (int ni = 0; ni < 7; ++ni)
        acc[mi][ni] = __builtin_amdgcn_mfma_f32_16x16x32_bf16(
            af[mi], bfr[ni], acc[mi][ni], 0, 0, 0);
  }

  if (wave < 2) {
#pragma unroll
    for (int mi = 0; mi < 4; ++mi) {
#pragma unroll
      for (int ni = 0; ni < 7; ++ni) {
        int pos = ni * 16 + l15;
        if (pos < 100) {
#pragma unroll
          for (int r = 0; r < 4; ++r) {
            int c = wave * 64 + mi * 16 + grp * 4 + r;
            resb[((long long)(b * COUT + c)) * TV + p0 + pos] = f2bf(acc[mi][ni][r]);
          }
        }
      }
    }
  } else {
#pragma unroll
    for (int mi = 0; mi < 4; ++mi) {
      int o0 = (wave - 2) * 64 + mi * 16 + grp * 4;
#pragma unroll
      for (int ni = 0; ni < 7; ++ni) {
        int pos = ni * 16 + l15;
        if (pos < 100) {
          us4 pk;
#pragma unroll
          for (int r = 0; r < 4; ++r) pk[r] = f2bf(acc[mi][ni][r]);
          *(us4*)&h[((long long)(b * TV + p0 + pos)) * COUT + o0] = pk;
        }
      }
    }
  }

  {
    float2* pw = &part_rs[(((long long)(blockIdx.y * 75 + blockIdx.x)) * 4 + wave) * 64];
#pragma unroll
    for (int mi = 0; mi < 4; ++mi) {
#pragma unroll
      for (int r = 0; r < 4; ++r) {
        float s = 0.f, q = 0.f;
#pragma unroll
        for (int ni = 0; ni < 7; ++ni) {
          float v = (ni < 6 || l15 < 4) ? acc[mi][ni][r] : 0.f;
          s += v; q += v * v;
        }
#pragma unroll
        for (int m = 1; m < 16; m <<= 1) {
          s += __shfl_xor(s, m);
          q += __shfl_xor(q, m);
        }
        if (l15 == 0) pw[mi * 16 + grp * 4 + r] = make_float2(s, q);
      }
    }
  }
}

// ---------------------------------------------------------------------------
// kC2v2: finalize res & sp BN from kA4 partials. grid 256. (unchanged r8)
// ---------------------------------------------------------------------------
__global__ __launch_bounds__(256) void kC2v2(
    const float2* __restrict__ part_rs,
    const float* __restrict__ g_r,  const float* __restrict__ be_r,
    const float* __restrict__ g_sp, const float* __restrict__ be_sp,
    float* __restrict__ scales)
{
  __shared__ float rs[256], rq[256];
  const int row = blockIdx.x;
  const int wave = row >> 6, local = row & 63;
  const int tid = threadIdx.x;
  float s = 0.f, q = 0.f;
  for (int bid = tid; bid < 2400; bid += 256) {
    float2 v = part_rs[((long long)bid * 4 + wave) * 64 + local];
    s += v.x; q += v.y;
  }
  rs[tid] = s; rq[tid] = q;
  __syncthreads();
  for (int st = 128; st > 0; st >>= 1) {
    if (tid < st) { rs[tid] += rs[tid + st]; rq[tid] += rq[tid + st]; }
    __syncthreads();
  }
  if (tid == 0) {
    const float n = (float)NPC;
    float m = rs[0] / n, var = rq[0] / n - m * m;
    float iv = rsqrtf(var + 1e-5f);
    if (row < 128) {
      float sc = g_r[row] * iv;
      scales[row] = sc; scales[128 + row] = be_r[row] - m * sc;
    } else {
      int c = row - 128;
      float sc = g_sp[c] * iv;
      scales[256 + c] = sc; scales[384 + c] = be_sp[c] - m * sc;
    }
  }
}

// ---------------------------------------------------------------------------
// kE7: temporal conv 9x1, implicit MFMA GEMM. NP=256 tile, 512 threads /
// 8 waves (2 wm x 4 wn), single 58KB LDS buffer, 2 blocks/CU (16 waves).
// Halo factor 456/256 = 1.78x (was 2.56x). BN_s+ReLU fused in swizzled
// staging (0 conflicts); fused BN_t stats; setprio around MFMA.
// grid (30, 32).
// ---------------------------------------------------------------------------
constexpr int NP    = 256;
constexpr int HALO  = 100;               // 4*25
constexpr int STAGE = NP + 2 * HALO;     // 456

__global__ __launch_bounds__(512, 2) void kE7(
    const unsigned short* __restrict__ h, const unsigned short* __restrict__ wb2,
    const float* __restrict__ scales, unsigned short* __restrict__ cvb,
    float2* __restrict__ part_t)
{
  __shared__ unsigned short hs[STAGE * 64];   // 58368 B
  const int tid  = threadIdx.x;
  const int lane = tid & 63;
  const int wave = tid >> 6;          // 0..7
  const int wm   = wave >> 2, wn = wave & 3;
  const int b    = blockIdx.y;
  const int p0   = blockIdx.x * NP;
  const int grp  = lane >> 4;
  const int l15  = lane & 15;
  const int slot = tid & 7;

  f32x4 acc[4][4];
#pragma unroll
  for (int m = 0; m < 4; ++m)
#pragma unroll
    for (int n = 0; n < 4; ++n) acc[m][n] = (f32x4)0.f;

  for (int cc = 0; cc < 2; ++cc) {
    if (cc) __syncthreads();             // previous chunk's MFMA reads done
    const int c0 = cc * 64;
    float sc[8], sh[8];
#pragma unroll
    for (int e = 0; e < 8; ++e) {
      sc[e] = scales[256 + c0 + slot * 8 + e];
      sh[e] = scales[384 + c0 + slot * 8 + e];
    }
    for (int i = tid; i < STAGE * 8; i += 512) {
      int pos = i >> 3;
      int pg = p0 - HALO + pos;
      us8 o = (us8)(unsigned short)0;
      if (pg >= 0 && pg < TV) {
        us8 v = *(const us8*)&h[((long long)b * TV + pg) * COUT + c0 + slot * 8];
#pragma unroll
        for (int e = 0; e < 8; ++e)
          o[e] = f2bf(fmaxf(bf2f(v[e]) * sc[e] + sh[e], 0.f));
      }
      int si = (pos << 6) + ((slot ^ (pos & 7)) << 3);
      *(us8*)&hs[si] = o;
    }
    __syncthreads();

    __builtin_amdgcn_s_setprio(1);
    for (int k = 0; k < 9; ++k) {
      const int plb = HALO + wn * 64 + 25 * (k - 4) + l15;
#pragma unroll
      for (int ks = 0; ks < 2; ++ks) {
        bf16x8 af[4], bfr[4];
#pragma unroll
        for (int mi = 0; mi < 4; ++mi) {
          int o = wm * 64 + mi * 16 + l15;
          af[mi] = *(const bf16x8*)&wb2[((k * 16 + cc * 8 + ks * 4 + grp) * 128 + o) * 8];
        }
#pragma unroll
        for (int ni = 0; ni < 4; ++ni) {
          int pl = plb + ni * 16;
          int si = (pl << 6) + (((ks * 4 + grp) ^ (pl & 7)) << 3);
          bfr[ni] = *(const bf16x8*)&hs[si];
        }
#pragma unroll
        for (int mi = 0; mi < 4; ++mi)
#pragma unroll
          for (int ni = 0; ni < 4; ++ni)
            acc[mi][ni] = __builtin_amdgcn_mfma_f32_16x16x32_bf16(
                af[mi], bfr[ni], acc[mi][ni], 0, 0, 0);
      }
    }
    __builtin_amdgcn_s_setprio(0);
  }

  // epilogue: conv -> cvb bf16
#pragma unroll
  for (int mi = 0; mi < 4; ++mi) {
#pragma unroll
    for (int ni = 0; ni < 4; ++ni) {
      int pos = p0 + wn * 64 + ni * 16 + l15;
      if (pos < TV) {
#pragma unroll
        for (int r = 0; r < 4; ++r) {
          int o = wm * 64 + mi * 16 + grp * 4 + r;
          cvb[((long long)(b * COUT + o)) * TV + pos] = f2bf(acc[mi][ni][r]);
        }
      }
    }
  }

  // fused BN_t stats partials: [bid][wave(8)][64]
  {
    float2* pw = &part_t[(((long long)(blockIdx.y * 30 + blockIdx.x)) * 8 + wave) * 64];
#pragma unroll
    for (int mi = 0; mi < 4; ++mi) {
#pragma unroll
      for (int r = 0; r < 4; ++r) {
        float s = 0.f, q = 0.f;
#pragma unroll
        for (int ni = 0; ni < 4; ++ni) {
          int pos = p0 + wn * 64 + ni * 16 + l15;
          float v = (pos < TV) ? acc[mi][ni][r] : 0.f;
          s += v; q += v * v;
        }
#pragma unroll
        for (int m = 1; m < 16; m <<= 1) {
          s += __shfl_xor(s, m);
          q += __shfl_xor(q, m);
        }
        if (l15 == 0) pw[mi * 16 + grp * 4 + r] = make_float2(s, q);
      }
    }
  }
}

// ---------------------------------------------------------------------------
// kG2: finalize temporal BN from kE7 partials. grid 128.
// channel c: waves wm*4+wn (wn 0..3) of each of 960 blocks.
// ---------------------------------------------------------------------------
__global__ __launch_bounds__(256) void kG2(
    const float2* __restrict__ part_t,
    const float* __restrict__ g_t, const float* __restrict__ be_t,
    float* __restrict__ scales)
{
  __shared__ float rs[256], rq[256];
  const int c = blockIdx.x;
  const int wm = c >> 6, local = c & 63;
  const int tid = threadIdx.x;
  const int NB = 30 * 32;              // 960 blocks
  float s = 0.f, q = 0.f;
  for (int p = tid; p < NB * 4; p += 256) {
    int bid = p >> 2, wn = p & 3;
    float2 v = part_t[((long long)bid * 8 + (wm * 4 + wn)) * 64 + local];
    s += v.x; q += v.y;
  }
  rs[tid] = s; rq[tid] = q;
  __syncthreads();
  for (int st = 128; st > 0; st >>= 1) {
    if (tid < st) { rs[tid] += rs[tid + st]; rq[tid] += rq[tid + st]; }
    __syncthreads();
  }
  if (tid == 0) {
    const float n = (float)NPC;
    float m = rs[0] / n, var = rq[0] / n - m * m;
    float sc = g_t[c] * rsqrtf(var + 1e-5f);
    scales[512 + c] = sc;
    scales[640 + c] = be_t[c] - m * sc;
  }
}

// ---------------------------------------------------------------------------
// kH: out = relu(cvb*sc_t+sh_t + resb*sc_r+sh_r). grid 4096 planes.
// ---------------------------------------------------------------------------
__global__ __launch_bounds__(256) void kH(
    const unsigned short* __restrict__ cvb, const unsigned short* __restrict__ resb,
    const float* __restrict__ scales, float* __restrict__ out)
{
  const int plane = blockIdx.x;
  const int c = plane & 127;
  const float sct = scales[512 + c], sht = scales[640 + c];
  const float scr = scales[c],       shr = scales[128 + c];
  const us4* cp = (const us4*)&cvb[(long long)plane * TV];
  const us4* rp = (const us4*)&resb[(long long)plane * TV];
  float* op = &out[(long long)plane * TV];
  for (int u = threadIdx.x; u < 1875; u += 256) {
    us4 o4 = cp[u], r4 = rp[u];
    float4 y;
    y.x = fmaxf(bf2f(o4[0]) * sct + sht + bf2f(r4[0]) * scr + shr, 0.f);
    y.y = fmaxf(bf2f(o4[1]) * sct + sht + bf2f(r4[1]) * scr + shr, 0.f);
    y.z = fmaxf(bf2f(o4[2]) * sct + sht + bf2f(r4[2]) * scr + shr, 0.f);
    y.w = fmaxf(bf2f(o4[3]) * sct + sht + bf2f(r4[3]) * scr + shr, 0.f);
    *(float4*)&op[u * 4] = y;
  }
}

// ---------------------------------------------------------------------------
extern "C" void kernel_launch(void* const* d_in, const int* in_sizes, int n_in,
                              void* d_out, int out_size, void* d_ws, size_t ws_size,
                              hipStream_t stream) {
  const float* x     = (const float*)d_in[0];
  const float* A_hat = (const float*)d_in[1];
  const float* w_sp  = (const float*)d_in[2];
  const float* g_sp  = (const float*)d_in[4];
  const float* be_sp = (const float*)d_in[5];
  const float* w_t   = (const float*)d_in[6];
  const float* g_t   = (const float*)d_in[8];
  const float* be_t  = (const float*)d_in[9];
  const float* w_r   = (const float*)d_in[10];
  const float* g_r   = (const float*)d_in[12];
  const float* be_r  = (const float*)d_in[13];
  float* out = (float*)d_out;

  // workspace carving (shorts)
  unsigned short* base_us = (unsigned short*)d_ws;
  unsigned short* resb = base_us;                          // TOTAL
  unsigned short* h    = base_us + (size_t)TOTAL;          // TOTAL
  unsigned short* cvb  = base_us + (size_t)(2 * TOTAL);    // TOTAL
  unsigned short* wb2  = base_us + (size_t)(3 * TOTAL);    // 147456
  unsigned short* wrs2 = wb2 + 147456;                     // 16384
  unsigned short* bdt  = wrs2 + 16384;                     // 14336
  float2* part_rs = (float2*)(bdt + 14336);                // 2400*4*64
  float2* part_t  = part_rs + 2400 * 4 * 64;               // 960*8*64
  float*  scales  = (float*)(part_t + 960 * 8 * 64);       // 768 floats

  // all prep in one launch
  kPrep<<<696, 256, 0, stream>>>(w_t, w_r, w_sp, A_hat, wb2, wrs2, bdt);
  // spatial front-end (stats fused)
  kA4<<<dim3(75, 32), 256, 0, stream>>>(x, bdt, wrs2, resb, h, part_rs);
  kC2v2<<<256, 256, 0, stream>>>(part_rs, g_r, be_r, g_sp, be_sp, scales);
  // temporal conv (NP=256 tile, fused BN_s+ReLU staging, stats fused)
  kE7<<<dim3(30, 32), 512, 0, stream>>>(h, wb2, scales, cvb, part_t);
  kG2<<<128, 256, 0, stream>>>(part_t, g_t, be_t, scales);
  // fused epilogue
  kH<<<4096, 256, 0, stream>>>(cvb, resb, scales, out);
}